// Round 1
// baseline (361.732 us; speedup 1.0000x reference)
//
#include <hip/hip_runtime.h>
#include <math.h>

#define D 512
#define K 14
#define EPS 1e-8f
#define NROWS 65536

// Output float offsets (reference tuple order, flattened)
#define O_SNN       0          // 16*4096
#define O_PHINA     65536      // 16*4096*13
#define O_SAN       917504     // 16*4096
#define O_SAA       983040     // 16*4096
#define O_PHIOTHER  1048576    // 16*4096*12
#define O_SAANORM   1835008    // 16*4096
#define O_PSEUDO    1900544    // 16*4096
#define O_SCORES    1966080    // 16*4096
#define O_TN        2031616    // 512

__device__ __forceinline__ float wave_sum(float v) {
    v += __shfl_xor(v, 1);
    v += __shfl_xor(v, 2);
    v += __shfl_xor(v, 4);
    v += __shfl_xor(v, 8);
    v += __shfl_xor(v, 16);
    v += __shfl_xor(v, 32);
    return v;
}
__device__ __forceinline__ float wave_min(float v) {
    v = fminf(v, __shfl_xor(v, 1));
    v = fminf(v, __shfl_xor(v, 2));
    v = fminf(v, __shfl_xor(v, 4));
    v = fminf(v, __shfl_xor(v, 8));
    v = fminf(v, __shfl_xor(v, 16));
    v = fminf(v, __shfl_xor(v, 32));
    return v;
}
__device__ __forceinline__ float wave_max(float v) {
    v = fmaxf(v, __shfl_xor(v, 1));
    v = fmaxf(v, __shfl_xor(v, 2));
    v = fmaxf(v, __shfl_xor(v, 4));
    v = fmaxf(v, __shfl_xor(v, 8));
    v = fmaxf(v, __shfl_xor(v, 16));
    v = fmaxf(v, __shfl_xor(v, 32));
    return v;
}

// Transpose-reduction: 16 per-lane accumulators -> full 64-lane sums.
// Result: lane l (l<16) holds the total of value bitrev4(l).
__device__ __forceinline__ float multi_reduce16(float (&vals)[16], int lane) {
#pragma unroll
    for (int s = 0; s < 4; s++) {
        const int half = 8 >> s;          // 8,4,2,1
        const bool sel = (lane >> s) & 1;
#pragma unroll
        for (int i = 0; i < half; i++) {
            float lo = vals[i], hi = vals[i + half];
            float a = sel ? lo : hi;
            float b = __shfl_xor(a, 1 << s);
            vals[i] = sel ? (hi + b) : (lo + b);
        }
    }
    float v = vals[0];
    v += __shfl_xor(v, 16);
    v += __shfl_xor(v, 32);
    return v;
}

__device__ __forceinline__ int bitrev4(int x) {
    return ((x & 1) << 3) | ((x & 2) << 1) | ((x & 4) >> 1) | ((x & 8) >> 3);
}

// Kernel A: normalize T_emb rows 0..13 into W[0..13], copy w_score into W[14],
// and write T_n_enhanced. One wave per row -> 15 blocks.
__global__ __launch_bounds__(64) void kprep(const float* __restrict__ T_emb,
                                            const float* __restrict__ w_score,
                                            float* __restrict__ W,
                                            float* __restrict__ tn_out) {
    int lane = threadIdx.x;
    int w = blockIdx.x; // 0..14
    float4* W4 = (float4*)W;
    if (w < K) {
        const float4* src = (const float4*)T_emb + w * 128;
        float4 a = src[lane];
        float4 b = src[64 + lane];
        float ss = a.x * a.x + a.y * a.y + a.z * a.z + a.w * a.w
                 + b.x * b.x + b.y * b.y + b.z * b.z + b.w * b.w;
        ss = wave_sum(ss);
        float inv = 1.0f / (sqrtf(ss) + EPS);
        float4 na = make_float4(a.x * inv, a.y * inv, a.z * inv, a.w * inv);
        float4 nb = make_float4(b.x * inv, b.y * inv, b.z * inv, b.w * inv);
        W4[w * 128 + lane] = na;
        W4[w * 128 + 64 + lane] = nb;
        if (w == K - 1) {
            float4* t4 = (float4*)tn_out;
            t4[lane] = na;
            t4[64 + lane] = nb;
        }
    } else {
        const float4* src = (const float4*)w_score;
        W4[14 * 128 + lane] = src[lane];
        W4[14 * 128 + 64 + lane] = src[64 + lane];
    }
}

template <int NK>
__device__ __forceinline__ void dotvals(float (&vals)[16],
                                        const float4 f0, const float4 f1,
                                        const float4 (&t0)[NK], const float4 (&t1)[NK]) {
#pragma unroll
    for (int k = 0; k < NK; k++) {
        float s = f0.x * t0[k].x;
        s = fmaf(f0.y, t0[k].y, s);
        s = fmaf(f0.z, t0[k].z, s);
        s = fmaf(f0.w, t0[k].w, s);
        s = fmaf(f1.x, t1[k].x, s);
        s = fmaf(f1.y, t1[k].y, s);
        s = fmaf(f1.z, t1[k].z, s);
        s = fmaf(f1.w, t1[k].w, s);
        vals[k] = s;
    }
#pragma unroll
    for (int k = NK; k < 16; k++) vals[k] = 0.0f;
}

template <bool ANOM>
__device__ __forceinline__ void finish_row(float (&vals)[16], int row, int lane, int myk,
                                           const int* __restrict__ cls, float bsc,
                                           float* __restrict__ S_nn, float* __restrict__ phi_na,
                                           float* __restrict__ S_an, float* __restrict__ S_aa,
                                           float* __restrict__ phi_other, float* __restrict__ scores) {
    float v = multi_reduce16(vals, lane);
    if (ANOM) {
        if (lane < 16 && myk < 15) {
            int ci = cls[row >> 12]; // wave-uniform
            float val = v;
            float* ptr;
            if (myk < 13) {
                ptr = (myk == ci) ? (S_aa + row)
                                  : (phi_other + row * 12 + ((myk < ci) ? myk : myk - 1));
            } else if (myk == 13) {
                ptr = S_an + row;
            } else {
                ptr = scores + row;
                val = 1.0f / (1.0f + expf(-(v + bsc)));
            }
            *ptr = val;
        }
    } else {
        if (lane < 16 && myk < 14) {
            float* ptr = (myk < 13) ? (phi_na + row * 13 + myk) : (S_nn + row);
            *ptr = v;
        }
    }
}

// 2-deep software pipeline: iteration body = { prefetch row i+2 ; FMA row i+1 ;
// shuffle-reduce + store row i }. The independent FMA stream hides the serial
// ds_swizzle chain of the reduce; the prefetch hides HBM latency under both.
template <bool ANOM>
__device__ __forceinline__ void run_half(const float4* __restrict__ feats,
                                         const float4* __restrict__ W4,
                                         const int* __restrict__ cls, float bsc,
                                         int wave, int nw, int lane, int myk,
                                         float* __restrict__ S_nn, float* __restrict__ phi_na,
                                         float* __restrict__ S_an, float* __restrict__ S_aa,
                                         float* __restrict__ phi_other, float* __restrict__ scores) {
    constexpr int NK = ANOM ? 15 : 14;
    float4 t0[NK], t1[NK];
#pragma unroll
    for (int k = 0; k < NK; k++) {
        t0[k] = W4[k * 128 + lane];
        t1[k] = W4[k * 128 + 64 + lane];
    }

    int pA = wave;           // row whose vals are pending reduce (in valsA)
    int pB = wave + nw;      // row whose data is loaded (in B regs)
    int pC = wave + 2 * nw;  // next row to prefetch

    float4 A0 = feats[pA * 128 + lane];
    float4 A1 = feats[pA * 128 + 64 + lane];
    float4 B0 = feats[pB * 128 + lane];
    float4 B1 = feats[pB * 128 + 64 + lane];
    float valsA[16], valsB[16];
    dotvals<NK>(valsA, A0, A1, t0, t1);

    const int niter = NROWS / nw; // 16 with the 1024-blocks-per-half grid (even, >=2)
#pragma unroll 1
    for (int it = 0; it < (niter - 2) / 2; ++it) {
        // phase 1: prefetch into A, FMA B, reduce valsA
        A0 = feats[pC * 128 + lane];
        A1 = feats[pC * 128 + 64 + lane];
        dotvals<NK>(valsB, B0, B1, t0, t1);
        finish_row<ANOM>(valsA, pA, lane, myk, cls, bsc, S_nn, phi_na, S_an, S_aa, phi_other, scores);
        pA = pB; pB = pC; pC += nw;
        // phase 2: prefetch into B, FMA A, reduce valsB
        B0 = feats[pC * 128 + lane];
        B1 = feats[pC * 128 + 64 + lane];
        dotvals<NK>(valsA, A0, A1, t0, t1);
        finish_row<ANOM>(valsB, pA, lane, myk, cls, bsc, S_nn, phi_na, S_an, S_aa, phi_other, scores);
        pA = pB; pB = pC; pC += nw;
    }
    // epilogue: two rows remain (valsA pending @ pA, B regs hold row pB)
    dotvals<NK>(valsB, B0, B1, t0, t1);
    finish_row<ANOM>(valsA, pA, lane, myk, cls, bsc, S_nn, phi_na, S_an, S_aa, phi_other, scores);
    finish_row<ANOM>(valsB, pB, lane, myk, cls, bsc, S_nn, phi_na, S_an, S_aa, phi_other, scores);
}

// Kernel B: both feature tensors in one launch. Blocks [0, half) -> normal,
// [half, 2*half) -> anomaly.
__global__ __launch_bounds__(256, 2) void kmain(const float4* __restrict__ nf,
                                                const float4* __restrict__ af,
                                                const float4* __restrict__ W4,
                                                const int* __restrict__ cls,
                                                const float* __restrict__ b_score,
                                                float* __restrict__ S_nn,
                                                float* __restrict__ phi_na,
                                                float* __restrict__ S_an,
                                                float* __restrict__ S_aa,
                                                float* __restrict__ phi_other,
                                                float* __restrict__ scores) {
    int lane = threadIdx.x & 63;
    int half = gridDim.x >> 1;
    int nw = half << 2; // waves per half = half*256/64
    bool anom = (int)blockIdx.x >= half;
    int bid = anom ? (int)blockIdx.x - half : (int)blockIdx.x;
    int wave = (bid << 2) + (threadIdx.x >> 6);
    int myk = bitrev4(lane);
    float bsc = *b_score;
    if (anom)
        run_half<true>(af, W4, cls, bsc, wave, nw, lane, myk,
                       S_nn, phi_na, S_an, S_aa, phi_other, scores);
    else
        run_half<false>(nf, W4, cls, bsc, wave, nw, lane, myk,
                        S_nn, phi_na, S_an, S_aa, phi_other, scores);
}

// Kernel C: per-batch min/max + normalize + fuse, one block per batch.
// All 32 values stay in registers across the reduction (no second read pass).
__global__ __launch_bounds__(256) void kpost(const float* __restrict__ S_aa,
                                             const float* __restrict__ S_an,
                                             float* __restrict__ S_aa_norm,
                                             float* __restrict__ pseudo) {
    int b = blockIdx.x;
    int t = threadIdx.x;
    int lane = t & 63, wid = t >> 6;
    const float* pa = S_aa + b * 4096;
    const float* pn = S_an + b * 4096;
    float a[16], n[16];
    float mnA = 1e30f, mxA = -1e30f, mnN = 1e30f, mxN = -1e30f;
#pragma unroll
    for (int i = 0; i < 16; i++) {
        a[i] = pa[t + i * 256];
        n[i] = pn[t + i * 256];
        mnA = fminf(mnA, a[i]); mxA = fmaxf(mxA, a[i]);
        mnN = fminf(mnN, n[i]); mxN = fmaxf(mxN, n[i]);
    }
    mnA = wave_min(mnA); mxA = wave_max(mxA);
    mnN = wave_min(mnN); mxN = wave_max(mxN);
    __shared__ float red[4][4];
    if (lane == 0) {
        red[wid][0] = mnA; red[wid][1] = mxA;
        red[wid][2] = mnN; red[wid][3] = mxN;
    }
    __syncthreads();
    mnA = fminf(fminf(red[0][0], red[1][0]), fminf(red[2][0], red[3][0]));
    mxA = fmaxf(fmaxf(red[0][1], red[1][1]), fmaxf(red[2][1], red[3][1]));
    mnN = fminf(fminf(red[0][2], red[1][2]), fminf(red[2][2], red[3][2]));
    mxN = fmaxf(fmaxf(red[0][3], red[1][3]), fmaxf(red[2][3], red[3][3]));
    float dA = mxA - mnA + EPS;
    float dN = mxN - mnN + EPS;
#pragma unroll
    for (int i = 0; i < 16; i++) {
        float s_aa = (a[i] - mnA) / dA;
        float s_an = (n[i] - mnN) / dN;
        float fused = 0.8f * s_aa + 0.2f * (1.0f - s_an);
        pseudo[b * 4096 + t + i * 256] = fused > 0.55f ? 1.0f : 0.0f;
        S_aa_norm[b * 4096 + t + i * 256] = s_aa;
    }
}

extern "C" void kernel_launch(void* const* d_in, const int* in_sizes, int n_in,
                              void* d_out, int out_size, void* d_ws, size_t ws_size,
                              hipStream_t stream) {
    const float* normal_feats  = (const float*)d_in[0];
    const float* anomaly_feats = (const float*)d_in[1];
    const int*   cls           = (const int*)d_in[2];
    const float* T_emb         = (const float*)d_in[3];
    const float* w_score       = (const float*)d_in[4];
    const float* b_score       = (const float*)d_in[5];
    float* out = (float*)d_out;

    float* W = (float*)d_ws; // 15*512 floats

    kprep<<<15, 64, 0, stream>>>(T_emb, w_score, W, out + O_TN);

    kmain<<<2048, 256, 0, stream>>>((const float4*)normal_feats,
                                    (const float4*)anomaly_feats,
                                    (const float4*)W, cls, b_score,
                                    out + O_SNN, out + O_PHINA, out + O_SAN, out + O_SAA,
                                    out + O_PHIOTHER, out + O_SCORES);

    kpost<<<16, 256, 0, stream>>>(out + O_SAA, out + O_SAN,
                                  out + O_SAANORM, out + O_PSEUDO);
}